// Round 14
// baseline (39.946 us; speedup 1.0000x reference)
//
#include <hip/hip_runtime.h>
#include <hip/hip_bf16.h>
#include <math.h>

#define NB 32      // B
#define NV 1024    // V
#define NFT 16     // F
#define NA 32      // A
#define NP 64      // P
#define NOUT 128   // NF
#define NC 96      // C = P + A
#define NC2 192    // 2C

#define NSPLIT 16            // V splits
#define VPB 64               // rows per block

typedef __attribute__((ext_vector_type(8))) short bf16x8;
typedef __attribute__((ext_vector_type(4))) float f32x4;

// ---------------------------------------------------------------------------
// K2p: fused vertex transform + partial (max,sum) aggregation.
// grid (B,16) x **1024 threads** (16 waves/block, 2 blocks/CU = 32 waves/CU —
// the occupancy axis never isolated before; __launch_bounds__(1024,8) caps
// VGPR at 64 so both blocks stay resident).
//  phase A: c = tid&127 (<96 active), rh = tid>>7 -> rows rh*8..+7.
//  phase B: thread owns 1a x 3c (32a x 32 c-triples); per row 3 LDS reads
//           (b32 e broadcast + b64 + b32 f) + 9 VALU.
// part layout: part[((b*16+vs)*32 + a)*192 + c] = max ; +96+c = sum
// ---------------------------------------------------------------------------
__global__ __launch_bounds__(1024, 8)
void k2p(const float* __restrict__ x,
         const float* __restrict__ W_flr,
         const float* __restrict__ b_flr,
         const float* __restrict__ W_s,
         const float* __restrict__ b_s,
         float* __restrict__ ewbuf,
         float* __restrict__ part) {
    __shared__ float xs[VPB][NFT];        // 4 KB
    __shared__ float fs[VPB][NC];         // 24 KB

    int b = blockIdx.x, vs = blockIdx.y, tid = threadIdx.x;
    int rowbase = b * NV + vs * VPB;

    // stage x: 1024 floats = 256 float4
    if (tid < 256) {
        const float4* xsrc = (const float4*)(x + (size_t)rowbase * NFT);
        ((float4*)xs)[tid] = xsrc[tid];
    }
    __syncthreads();

    // phase A: c = tid&127 (<96 active), rh = tid>>7 -> rows rh*8..rh*8+7
    {
        int c  = tid & 127;
        int rh = tid >> 7;
        if (c < NC) {
            float Wcol[NFT], bias;
            if (c < NP) {
                bias = b_flr[c];
#pragma unroll
                for (int k = 0; k < NFT; ++k) Wcol[k] = W_flr[k * NP + c];
            } else {
                int a = c - NP;
                bias = b_s[a];
#pragma unroll
                for (int k = 0; k < NFT; ++k) Wcol[k] = W_s[k * NA + a];
            }
#pragma unroll
            for (int r0 = 0; r0 < 8; ++r0) {
                int r = rh * 8 + r0;
                float acc = bias;
#pragma unroll
                for (int q = 0; q < 4; ++q) {
                    float4 xv = ((const float4*)xs[r])[q];
                    acc = fmaf(xv.x, Wcol[q * 4 + 0], acc);
                    acc = fmaf(xv.y, Wcol[q * 4 + 1], acc);
                    acc = fmaf(xv.z, Wcol[q * 4 + 2], acc);
                    acc = fmaf(xv.w, Wcol[q * 4 + 3], acc);
                }
                if (c >= NP) {
                    acc = __expf(-acc * acc);
                    ewbuf[(size_t)(rowbase + r) * NA + (c - NP)] = acc;
                }
                fs[r][c] = acc;
            }
        }
    }
    __syncthreads();

    // phase B: thread owns 1a x 3c. a = tid>>5 (32), c0 = (tid&31)*3.
    int a  = tid >> 5;
    int c0 = (tid & 31) * 3;
    int ea = NP + a;

    float sm[3], mx[3];
#pragma unroll
    for (int j = 0; j < 3; ++j) { sm[j] = 0.f; mx[j] = -INFINITY; }

#pragma unroll 8
    for (int r = 0; r < VPB; ++r) {
        float e = fs[r][ea];
        float2 fA = *(const float2*)&fs[r][c0];
        float f1 = fs[r][c0 + 2];
        float p0 = e * fA.x, p1 = e * fA.y, p2 = e * f1;
        sm[0] += p0; sm[1] += p1; sm[2] += p2;
        mx[0] = fmaxf(mx[0], p0);
        mx[1] = fmaxf(mx[1], p1);
        mx[2] = fmaxf(mx[2], p2);
    }

    float* pb = part + (size_t)((b * NSPLIT + vs) * NA + a) * NC2;
    float2 vm = {mx[0], mx[1]};
    float2 vs2 = {sm[0], sm[1]};
    *(float2*)&pb[c0] = vm;
    pb[c0 + 2] = mx[2];
    *(float2*)&pb[NC + c0] = vs2;
    pb[NC + c0 + 2] = sm[2];
}

// ---------------------------------------------------------------------------
// K23: combine NSPLIT partials -> agg (LDS) -> G matmul. (unchanged)
// ---------------------------------------------------------------------------
__global__ void k23(const float* __restrict__ part,
                    const float* __restrict__ W_out,
                    float* __restrict__ Gp) {
    __shared__ float aggL[NC2];
    int b = blockIdx.x, a = blockIdx.y, tid = threadIdx.x;

    {
        const float* pb = part + (size_t)(b * NSPLIT * NA + a) * NC2 + tid;
        const size_t stride = (size_t)NA * NC2;
        if (tid < NC) {
            float m = -INFINITY;
#pragma unroll
            for (int vsi = 0; vsi < NSPLIT; ++vsi)
                m = fmaxf(m, pb[vsi * stride]);
            aggL[tid] = m;
        } else {
            float s = 0.f;
#pragma unroll
            for (int vsi = 0; vsi < NSPLIT; ++vsi)
                s += pb[vsi * stride];
            aggL[tid] = s * (1.0f / (float)NV);
        }
    }
    __syncthreads();

    if (tid < NOUT) {
        int n = tid;
        const float* wr = W_out + (size_t)(NFT + a * NC2) * NOUT + n;
        float acc = W_out[(size_t)(NFT + NA * NC2 + a) * NOUT + n];
#pragma unroll 8
        for (int c = 0; c < NC2; ++c)
            acc = fmaf(aggL[c], wr[(size_t)c * NOUT], acc);
        Gp[(size_t)(b * NA + a) * NOUT + n] = acc;
    }
}

// ---------------------------------------------------------------------------
// K4 (MFMA, conflict-free fragment-order layout). (unchanged R13)
// ---------------------------------------------------------------------------
#define MB 64

__device__ inline void f2hl(float v, ushort& h, ushort& l) {
    __hip_bfloat16 hb = __float2bfloat16(v);
    float hf = __bfloat162float(hb);
    __hip_bfloat16 lb = __float2bfloat16(v - hf);
    h = *(ushort*)&hb;
    l = *(ushort*)&lb;
}

__global__ void k4_mfma(const float* __restrict__ x,
                        const float* __restrict__ ewbuf,
                        const float* __restrict__ Gp,
                        const float* __restrict__ W_out,
                        const float* __restrict__ b_out,
                        float* __restrict__ out) {
    __shared__ ushort BsH[1024 * 8];   // 16 KB
    __shared__ ushort BsL[1024 * 8];   // 16 KB
    __shared__ float  bs[NOUT];

    int rb = blockIdx.x;
    int b  = blockIdx.y;
    int tid = threadIdx.x;
    int rowbase = b * NV + rb * MB;

    // ---- stage B in fragment-order ----
#pragma unroll
    for (int it = 0; it < 4; ++it) {
        int u = it * 256 + tid;
        int n = u & 127, koct = u >> 7;
        float v[8];
        if (koct < 2) {
#pragma unroll
            for (int j = 0; j < 8; ++j)
                v[j] = W_out[(size_t)(koct * 8 + j) * NOUT + n];
        } else if (koct < 6) {
#pragma unroll
            for (int j = 0; j < 8; ++j)
                v[j] = Gp[(size_t)b * NA * NOUT + (size_t)(koct * 8 + j - 16) * NOUT + n];
        } else {
#pragma unroll
            for (int j = 0; j < 8; ++j) v[j] = 0.f;
        }
        ushort h[8], l[8];
#pragma unroll
        for (int j = 0; j < 8; ++j) f2hl(v[j], h[j], l[j]);
        int cidx = ((koct >> 2) * 512) + ((n >> 4) * 64) + ((koct & 3) * 16) + (n & 15);
        *(bf16x8*)&BsH[cidx * 8] = *(bf16x8*)h;
        *(bf16x8*)&BsL[cidx * 8] = *(bf16x8*)l;
    }
    if (tid < NOUT) bs[tid] = b_out[tid];

    // ---- A fragments direct from global ----
    int w = tid >> 6, lane = tid & 63;
    int r16 = lane & 15, kg = lane >> 4;
    int arow = w * 16 + r16;
    int grow = rowbase + arow;

    float a0[8], a1[8];
    if (kg < 2) {
        *(float4*)&a0[0] = *(const float4*)&x[(size_t)grow * NFT + kg * 8];
        *(float4*)&a0[4] = *(const float4*)&x[(size_t)grow * NFT + kg * 8 + 4];
        *(float4*)&a1[0] = *(const float4*)&ewbuf[(size_t)grow * NA + 16 + kg * 8];
        *(float4*)&a1[4] = *(const float4*)&ewbuf[(size_t)grow * NA + 16 + kg * 8 + 4];
    } else {
        *(float4*)&a0[0] = *(const float4*)&ewbuf[(size_t)grow * NA + (kg - 2) * 8];
        *(float4*)&a0[4] = *(const float4*)&ewbuf[(size_t)grow * NA + (kg - 2) * 8 + 4];
#pragma unroll
        for (int j = 0; j < 8; ++j) a1[j] = 0.f;
    }
    ushort ah0[8], al0[8], ah1[8], al1[8];
#pragma unroll
    for (int j = 0; j < 8; ++j) f2hl(a0[j], ah0[j], al0[j]);
#pragma unroll
    for (int j = 0; j < 8; ++j) f2hl(a1[j], ah1[j], al1[j]);
    bf16x8 AH0 = *(bf16x8*)ah0, AL0 = *(bf16x8*)al0;
    bf16x8 AH1 = *(bf16x8*)ah1, AL1 = *(bf16x8*)al1;

    __syncthreads();

    int orow0 = rowbase + w * 16 + kg * 4;

#pragma unroll
    for (int nt = 0; nt < 8; ++nt) {
        int n = nt * 16 + r16;
        bf16x8 BH0 = *(const bf16x8*)&BsH[(nt * 64 + lane) * 8];
        bf16x8 BH1 = *(const bf16x8*)&BsH[(512 + nt * 64 + lane) * 8];
        bf16x8 BL0 = *(const bf16x8*)&BsL[(nt * 64 + lane) * 8];
        bf16x8 BL1 = *(const bf16x8*)&BsL[(512 + nt * 64 + lane) * 8];
        float bias = bs[n];
        f32x4 acc = {bias, bias, bias, bias};
        acc = __builtin_amdgcn_mfma_f32_16x16x32_bf16(AH0, BH0, acc, 0, 0, 0);
        acc = __builtin_amdgcn_mfma_f32_16x16x32_bf16(AL0, BH0, acc, 0, 0, 0);
        acc = __builtin_amdgcn_mfma_f32_16x16x32_bf16(AH0, BL0, acc, 0, 0, 0);
        acc = __builtin_amdgcn_mfma_f32_16x16x32_bf16(AH1, BH1, acc, 0, 0, 0);
        acc = __builtin_amdgcn_mfma_f32_16x16x32_bf16(AL1, BH1, acc, 0, 0, 0);
        acc = __builtin_amdgcn_mfma_f32_16x16x32_bf16(AH1, BL1, acc, 0, 0, 0);
#pragma unroll
        for (int rg = 0; rg < 4; ++rg) {
            float s = acc[rg];
            s = fminf(fmaxf(s, -15.f), 15.f);
            float e = __expf(2.f * s);
            out[(size_t)(orow0 + rg) * NOUT + n] =
                (e - 1.f) * __builtin_amdgcn_rcpf(e + 1.f);
        }
    }
}

// ---------------------------------------------------------------------------
extern "C" void kernel_launch(void* const* d_in, const int* in_sizes, int n_in,
                              void* d_out, int out_size, void* d_ws, size_t ws_size,
                              hipStream_t stream) {
    const float* x     = (const float*)d_in[0];
    const float* W_flr = (const float*)d_in[1];
    const float* b_flr = (const float*)d_in[2];
    const float* W_s   = (const float*)d_in[3];
    const float* b_s   = (const float*)d_in[4];
    const float* W_out = (const float*)d_in[5];
    const float* b_out = (const float*)d_in[6];
    float* out = (float*)d_out;

    // workspace layout (floats)
    float* ewbuf = (float*)d_ws;                              // B*V*32     = 1,048,576
    float* part  = ewbuf + (size_t)NB * NV * NA;              // 512*32*192 = 3,145,728
    float* Gp    = part  + (size_t)NB * NSPLIT * NA * NC2;    // B*A*128    =   131,072

    // K2p: grid (B, 16) x 1024
    {
        dim3 g(NB, NSPLIT);
        k2p<<<g, 1024, 0, stream>>>(x, W_flr, b_flr, W_s, b_s, ewbuf, part);
    }
    // K23: grid (B, A) x 192
    {
        dim3 g(NB, NA);
        k23<<<g, 192, 0, stream>>>(part, W_out, Gp);
    }
    // K4: grid (16 row-blocks, B) x 256
    {
        dim3 g(NV / MB, NB);
        k4_mfma<<<g, 256, 0, stream>>>(x, ewbuf, Gp, W_out, b_out, out);
    }
}